// Round 18
// baseline (3651.766 us; speedup 1.0000x reference)
//
#include <hip/hip_runtime.h>
#include <math.h>

#define BB 64
#define TT 256
#define HH 512
#define TH (TT*HH)
#define BTH (BB*TT*HH)

typedef __attribute__((ext_vector_type(8))) short short8;
typedef __attribute__((ext_vector_type(4))) float f32x4;

__device__ __forceinline__ unsigned short f32_bf16(float f) {
    unsigned int u = __float_as_uint(f);
    return (unsigned short)((u + 0x7fffu + ((u >> 16) & 1u)) >> 16);
}

// fast, overflow-safe gate nonlinearities (v_exp_f32 path; absmax-validated)
__device__ __forceinline__ float sigm_f(float x) {
    return 1.f / (1.f + __expf(-x));
}
__device__ __forceinline__ float tanh_f(float x) {
    return 1.f - 2.f / (__expf(2.f * x) + 1.f);
}

// coherent 16B fragment load: 2x u64 relaxed agent atomics
__device__ __forceinline__ short8 ld_coh(const short* p) {
    const unsigned long long* q = (const unsigned long long*)p;
    unsigned long long a = __hip_atomic_load(q,     __ATOMIC_RELAXED, __HIP_MEMORY_SCOPE_AGENT);
    unsigned long long b = __hip_atomic_load(q + 1, __ATOMIC_RELAXED, __HIP_MEMORY_SCOPE_AGENT);
    union { unsigned long long u[2]; short8 s; } r;
    r.u[0] = a; r.u[1] = b;
    return r.s;
}

// ---- one-time: weights fp32 -> bf16, fragment-major slabs (R8 layout) ----
struct WConv2 {
    const float* src[3][4];
    int rs[3][4];
    int co[3][4];
    int nch[3];
    int cnt[3];
    unsigned int slab[3];
    short* dst;
};
__global__ __launch_bounds__(256) void conv_w(WConv2 a) {
    const int l = blockIdx.y;
    const int i = blockIdx.x * 256 + threadIdx.x;
    if (i >= a.cnt[l]) return;
    const int NCH = a.nch[l];
    const int lane = i & 63;
    const int r = i >> 6;
    const int scc = r % NCH;
    const int wv = r / NCH;
    const int kh = wv & 1;
    const int nt = (wv >> 1) & 3;
    const int nb = wv >> 3;
    const int seg = scc >> 3;
    const int cc = scc & 7;
    const int hcol = nb*16 + nt*4 + ((lane & 15) >> 2);
    const int q = lane & 3;
    const int row = q*512 + hcol;
    const int k = a.co[l][seg] + (cc*2 + kh)*32 + (lane >> 4)*8;
    const float* s = a.src[l][seg] + (size_t)row * a.rs[l][seg] + k;
    float4 v0 = *(const float4*)s;
    float4 v1 = *(const float4*)(s + 4);
    short8 o;
    o[0]=f32_bf16(v0.x); o[1]=f32_bf16(v0.y); o[2]=f32_bf16(v0.z); o[3]=f32_bf16(v0.w);
    o[4]=f32_bf16(v1.x); o[5]=f32_bf16(v1.y); o[6]=f32_bf16(v1.z); o[7]=f32_bf16(v1.w);
    *(short8*)(a.dst + (size_t)a.slab[l] + (size_t)i * 8) = o;
}

// ---- one-time: x fp32 -> bf16 fragment-major (A-side) ----
struct XConv {
    const float* src[3];
    short* dst;
};
__global__ __launch_bounds__(256) void conv_x(XConv a) {
    const int l = blockIdx.y;
    const int i = blockIdx.x * 256 + threadIdx.x;
    const int lane = i & 63;
    const int kc = (i >> 6) & 15;
    const int btt = i >> 10;
    const int bt = btt & 3;
    const int t = btt >> 2;
    const int b = bt * 16 + (lane & 15);
    const int k = kc * 32 + (lane >> 4) * 8;
    const float* s = a.src[l] + ((size_t)b * TT + t) * HH + k;
    float4 v0 = *(const float4*)s;
    float4 v1 = *(const float4*)(s + 4);
    short8 o;
    o[0]=f32_bf16(v0.x); o[1]=f32_bf16(v0.y); o[2]=f32_bf16(v0.z); o[3]=f32_bf16(v0.w);
    o[4]=f32_bf16(v1.x); o[5]=f32_bf16(v1.y); o[6]=f32_bf16(v1.z); o[7]=f32_bf16(v1.w);
    *(short8*)(a.dst + (size_t)l * 8388608 + (size_t)i * 8) = o;
}

struct PersArgs {
    const short* wreg; const short* xreg; short* hreg;
    const float* dx; float* out; int* flags;
    const float* bih[3]; const float* bhh[3];
};

// x segment: plain-cached A loads, weights read from global slab (WOFF =
// chunk offset in the wave's slab block). Off-critical-path (pre-poll).
#define SEG_MFMA_PLAIN_GW(WOFF, ASRC, SCP)                                     \
    {                                                                          \
        const short* ap_ = (ASRC) + (size_t)lane * 8;                          \
        _Pragma("unroll")                                                      \
        for (int cc = 0; cc < 8; ++cc) {                                       \
            const int cis = cc*2 + kh;                                         \
            short8 wv8 = *(const short8*)(wgl + (size_t)((WOFF) + cc) * 512);  \
            short8 av[4];                                                      \
            _Pragma("unroll")                                                  \
            for (int mt = 0; mt < 4; ++mt)                                     \
                av[mt] = *(const short8*)(ap_ + (size_t)(mt*16 + cis) * 512);  \
            _Pragma("unroll")                                                  \
            for (int mt = 0; mt < 4; ++mt) {                                   \
                short8 xa = ((SCP) == nullptr || (SCP)[mt] != 0.f) ? av[mt] : vz; \
                acc[mt] = __builtin_amdgcn_mfma_f32_16x16x32_bf16(             \
                    xa, wv8, acc[mt], 0, 0, 0);                                \
            }                                                                  \
        }                                                                      \
    }

// consume one staged half from LDS; weights from REGISTER array w[]
#define SEG_LDSMM_H(SB, ABUF, SCP, MT0)                                        \
    _Pragma("unroll")                                                          \
    for (int cc = 0; cc < 8; ++cc) {                                           \
        _Pragma("unroll")                                                      \
        for (int m2 = 0; m2 < 2; ++m2) {                                       \
            short8 av = *(const short8*)((ABUF) + (size_t)(m2*16 + cc*2 + kh)*512 + lane*8); \
            short8 xa = ((SCP) == nullptr || (SCP)[(MT0)+m2] != 0.f) ? av : vz; \
            acc[(MT0)+m2] = __builtin_amdgcn_mfma_f32_16x16x32_bf16(           \
                xa, w[(SB) + cc], acc[(MT0)+m2], 0, 0, 0);                     \
        }                                                                      \
    }

// consume one staged half from LDS; weights from GLOBAL slab (hh path)
#define SEG_LDSMM_H_GW(WOFF, ABUF, SCP, MT0)                                   \
    _Pragma("unroll")                                                          \
    for (int cc = 0; cc < 8; ++cc) {                                           \
        short8 wv8 = *(const short8*)(wgl + (size_t)((WOFF) + cc) * 512);      \
        _Pragma("unroll")                                                      \
        for (int m2 = 0; m2 < 2; ++m2) {                                       \
            short8 av = *(const short8*)((ABUF) + (size_t)(m2*16 + cc*2 + kh)*512 + lane*8); \
            short8 xa = ((SCP) == nullptr || (SCP)[(MT0)+m2] != 0.f) ? av : vz; \
            acc[(MT0)+m2] = __builtin_amdgcn_mfma_f32_16x16x32_bf16(           \
                xa, wv8, acc[(MT0)+m2], 0, 0, 0);                              \
        }                                                                      \
    }

// staged coherent segment core: both halves' loads issued up front; raw
// lgkm-only barrier after half-A writes (half-B loads stay in flight and
// hide under {write A, barrier, MFMA A}); MFMA bodies passed as arguments.
#define SEG_COH_CORE(ASRC, MMA_A, MMA_B)                                       \
    {                                                                          \
        const short* spA_ = (ASRC) + ((size_t)(wv*4))*512 + lane*8;            \
        const short* spB_ = (ASRC) + ((size_t)(32 + wv*4))*512 + lane*8;       \
        short8 a0_ = ld_coh(spA_);                                             \
        short8 a1_ = ld_coh(spA_ + 512);                                       \
        short8 a2_ = ld_coh(spA_ + 1024);                                      \
        short8 a3_ = ld_coh(spA_ + 1536);                                      \
        short8 b0_ = ld_coh(spB_);                                             \
        short8 b1_ = ld_coh(spB_ + 512);                                       \
        short8 b2_ = ld_coh(spB_ + 1024);                                      \
        short8 b3_ = ld_coh(spB_ + 1536);                                      \
        {                                                                      \
            short* dp_ = abufA + (wv*4)*512 + lane*8;                          \
            *(short8*)(dp_)        = a0_;                                      \
            *(short8*)(dp_ + 512)  = a1_;                                      \
            *(short8*)(dp_ + 1024) = a2_;                                      \
            *(short8*)(dp_ + 1536) = a3_;                                      \
        }                                                                      \
        asm volatile("s_waitcnt lgkmcnt(0)" ::: "memory");                     \
        __builtin_amdgcn_s_barrier();                                          \
        __builtin_amdgcn_sched_barrier(0);                                     \
        MMA_A                                                                  \
        {                                                                      \
            short* dpB_ = abufB + (wv*4)*512 + lane*8;                         \
            *(short8*)(dpB_)        = b0_;                                     \
            *(short8*)(dpB_ + 512)  = b1_;                                     \
            *(short8*)(dpB_ + 1024) = b2_;                                     \
            *(short8*)(dpB_ + 1536) = b3_;                                     \
        }                                                                      \
        __syncthreads();                                                       \
        MMA_B                                                                  \
    }

#define SEG_COH_LDS(SB, ASRC, SCP)                                             \
    SEG_COH_CORE(ASRC, SEG_LDSMM_H(SB, abufA, SCP, 0);,                        \
                       SEG_LDSMM_H(SB, abufB, SCP, 2);)

#define SEG_COH_LDS_GW(WOFF, ASRC, SCP)                                        \
    SEG_COH_CORE(ASRC, SEG_LDSMM_H_GW(WOFF, abufA, SCP, 0);,                   \
                       SEG_LDSMM_H_GW(WOFF, abufB, SCP, 2);)

template<int L>
__device__ __forceinline__ void run_layer(const PersArgs& a, int nb,
                                          char* smem) {
    constexpr int NCHF = (L == 1) ? 32 : 24;     // full chunks in slab
    constexpr int NCHR = NCHF - 16;              // register chunks: td(+bu)
    constexpr int SB_TD = 0;                     // l0/l1 td at w[0..7]
    constexpr int SB_BU = (L == 1) ? 8 : 0;      // l1 bu at w[8..15]; l2 bu at w[0..7]
    constexpr unsigned int WSLAB = (L == 0) ? 0u : ((L == 1) ? 3145728u : 7340032u);
    short* abufA = (short*)smem;
    short* abufB = (short*)(smem + 32768);
    float* gsh   = (float*)smem;                 // aliases abufA (see R17 proof)
    #define GSH(khi, nti, mti, ri, ci) gsh[((((khi)*4 + (nti))*4 + (mti))*16 + (ri))*16 + (ci)]

    const int tid  = threadIdx.x;
    const int lane = tid & 63;
    const int wv   = tid >> 6;
    const int nt   = wv >> 1;
    const int kh   = wv & 1;
    const int r16  = lane & 15;
    const short8 vz = {0,0,0,0,0,0,0,0};

    // wave's slab base (global): x chunks 0..7, hh 8..15, td 16.., bu 24..
    const short* wgl_base = a.wreg + WSLAB
        + ((size_t)((nb*8 + nt*2 + kh) * NCHF)) * 512 + lane * 8;
    const short* wgl = wgl_base;                 // GW segments index from here

    // register weights: td(+bu) = slab chunks 16..NCHF-1
    short8 w[NCHR];
    #pragma unroll
    for (int i = 0; i < NCHR; ++i)
        w[i] = *(const short8*)(wgl_base + (size_t)(16 + i) * 512);

    const int eb_b = tid >> 3;
    const int ehp  = tid & 7;
    float bias[2][4];
    #pragma unroll
    for (int e = 0; e < 2; ++e) {
        const int ec = nb*16 + 2*ehp + e;
        #pragma unroll
        for (int q = 0; q < 4; ++q)
            bias[e][q] = a.bih[L][q*512 + ec] + a.bhh[L][q*512 + ec];
    }
    float c_reg[2] = {0.f, 0.f}, h_reg[2] = {0.f, 0.f};
    float hprev[2] = {0.f, 0.f};

    auto poll32 = [&](int st) {
        if (wv == 0) {
            const int* f = a.flags + st*32;
            for (;;) {
                int v = 1;
                if (lane < 32)
                    v = __hip_atomic_load(f + lane, __ATOMIC_RELAXED, __HIP_MEMORY_SCOPE_AGENT);
                if (__all(v != 0)) break;
                __builtin_amdgcn_s_sleep(1);
            }
        }
        __syncthreads();
    };

    for (int t = 0; t < TT; ++t) {
        const int pprev = (t - 1) & 1, pcur = t & 1;
        float dbv[4], dvv[4];
        #pragma unroll
        for (int mt = 0; mt < 4; ++mt) {
            const int b = mt*16 + r16;
            dbv[mt] = (L == 0) ? 1.f : a.dx[b*768 + (L-1)*256 + t];
            dvv[mt] = (t == 0) ? 0.f : a.dx[b*768 + L*256 + (t-1)];
        }
        f32x4 acc[4];
        #pragma unroll
        for (int mt = 0; mt < 4; ++mt) acc[mt] = (f32x4){0.f, 0.f, 0.f, 0.f};

        // ---- x segment: no dependency, pre-poll; weights from global ----
        SEG_MFMA_PLAIN_GW(0, a.xreg + (size_t)L*8388608 + (size_t)t*32768,
                          (L == 0) ? (const float*)nullptr : dbv);

        if (t > 0) {
            // ---- hh: 2-links stale, poll first; weights from global ----
            poll32((t-1)*3 + L);
            {
                union { float f[2]; unsigned long long u; } pk;
                pk.f[0] = hprev[0]; pk.f[1] = hprev[1];
                __builtin_nontemporal_store(pk.u,
                    (unsigned long long*)(a.out + (size_t)L*BTH + (size_t)eb_b*TH
                                          + (size_t)(t-1)*HH + nb*16 + 2*ehp));
            }
            SEG_COH_LDS_GW(8, a.hreg + (size_t)(L*2 + pprev)*32768, (const float*)nullptr);
            // ---- td: fresh; weights from REGISTERS ----
            if (L < 2) {
                poll32((t-1)*3 + L + 1);
                SEG_COH_LDS(SB_TD, a.hreg + (size_t)((L+1)*2 + pprev)*32768, dvv);
            }
        }
        // ---- bu: freshest; weights from REGISTERS ----
        if (L > 0) {
            poll32(t*3 + L - 1);
            SEG_COH_LDS(SB_BU, a.hreg + (size_t)((L-1)*2 + pcur)*32768, dbv);
        }

        // ---- acc -> LDS exchange (gsh aliases abufA; last segment's
        //      barrier 2 separates its MFMA-A reads) ----
        #pragma unroll
        for (int mt = 0; mt < 4; ++mt)
            #pragma unroll
            for (int r = 0; r < 4; ++r)
                GSH(kh, nt, mt, (lane >> 4)*4 + r, r16) = acc[mt][r];
        __syncthreads();

        // ---- cell epilogue: 512 threads x 2 hcols ----
        float hval[2];
        {
            const float db2 = (L == 0) ? 1.f : a.dx[eb_b*768 + (L-1)*256 + t];
            const float d2  = (t == 0) ? 0.f : a.dx[eb_b*768 + L*256 + (t-1)];
            const bool copy = (db2 + d2 == 0.f);
            const int mt = eb_b >> 4, row = eb_b & 15;
            #pragma unroll
            for (int e = 0; e < 2; ++e) {
                const int hl = 2*ehp + e;
                const int ntE = hl >> 2, cb = (hl & 3)*4;
                float G[4];
                #pragma unroll
                for (int q = 0; q < 4; ++q)
                    G[q] = GSH(0, ntE, mt, row, cb+q) + GSH(1, ntE, mt, row, cb+q) + bias[e][q];
                const float i_ = sigm_f(G[0]);
                const float f_ = sigm_f(G[1]);
                const float g_ = tanh_f(G[2]);
                const float o_ = sigm_f(G[3]);
                const float cold = c_reg[e] * (1.f - d2);
                const float cn = f_*cold + i_*g_;
                const float hn = o_*tanh_f(cn);
                hval[e] = copy ? h_reg[e] : hn;
                c_reg[e] = copy ? cold : cn;
                h_reg[e] = hval[e];
            }
            unsigned int pack = (unsigned int)f32_bf16(hval[0])
                              | ((unsigned int)f32_bf16(hval[1]) << 16);
            const int k  = nb*16 + 2*ehp;
            const int kc = k >> 5, kk = k & 31;
            const int lhi = kk >> 3, j = kk & 7;
            unsigned int* dst = (unsigned int*)(a.hreg + (size_t)(L*2 + pcur)*32768)
                + ((((size_t)(mt*16 + kc))*64 + lhi*16 + row)*8 + j) / 2;
            __hip_atomic_store(dst, pack, __ATOMIC_RELAXED, __HIP_MEMORY_SCOPE_AGENT);
        }
        __syncthreads();   // vmcnt drained -> pack stores visible

        if (tid == 0)
            __hip_atomic_store(a.flags + (t*3 + L)*32 + nb, 1,
                               __ATOMIC_RELAXED, __HIP_MEMORY_SCOPE_AGENT);

        hprev[0] = hval[0]; hprev[1] = hval[1];
    }
    {
        union { float f[2]; unsigned long long u; } pk;
        pk.f[0] = hprev[0]; pk.f[1] = hprev[1];
        __builtin_nontemporal_store(pk.u,
            (unsigned long long*)(a.out + (size_t)L*BTH + (size_t)eb_b*TH
                                  + (size_t)(TT-1)*HH + nb*16 + 2*ehp));
    }
    #undef GSH
}

__global__ __launch_bounds__(512, 2) void persistent_kernel(PersArgs a) {
    __shared__ char smem[65536];
    const int bid = blockIdx.x;
    if (bid < 32)       run_layer<0>(a, bid, smem);
    else if (bid < 64)  run_layer<1>(a, bid - 32, smem);
    else                run_layer<2>(a, bid - 64, smem);
}

extern "C" void kernel_launch(void* const* d_in, const int* in_sizes, int n_in,
                              void* d_out, int out_size, void* d_ws, size_t ws_size,
                              hipStream_t stream) {
    const float* x[3]    = {(const float*)d_in[0], (const float*)d_in[1], (const float*)d_in[2]};
    const float* dx      = (const float*)d_in[3];
    const float* W_ih[3] = {(const float*)d_in[4], (const float*)d_in[8],  (const float*)d_in[12]};
    const float* W_hh[3] = {(const float*)d_in[5], (const float*)d_in[9],  (const float*)d_in[13]};
    const float* b_ih[3] = {(const float*)d_in[6], (const float*)d_in[10], (const float*)d_in[14]};
    const float* b_hh[3] = {(const float*)d_in[7], (const float*)d_in[11], (const float*)d_in[15]};
    float* out = (float*)d_out;

    char* ws = (char*)d_ws;
    const size_t SZ_FLAGS = 98304;
    const size_t SZ_WREG  = 20971520;
    const size_t SZ_XREG  = 50331648;
    int*   flags = (int*)ws;
    short* wreg  = (short*)(ws + SZ_FLAGS);
    short* xreg  = (short*)(ws + SZ_FLAGS + SZ_WREG);
    short* hreg  = (short*)(ws + SZ_FLAGS + SZ_WREG + SZ_XREG);

    hipMemsetAsync(flags, 0, SZ_FLAGS, stream);

    {   // weight conversion: seg order per layer = [x, hh, td, bu] (R8 slabs)
        WConv2 wa;
        wa.src[0][0]=W_ih[0]; wa.rs[0][0]=1024; wa.co[0][0]=0;
        wa.src[0][1]=W_hh[0]; wa.rs[0][1]=512;  wa.co[0][1]=0;
        wa.src[0][2]=W_ih[0]; wa.rs[0][2]=1024; wa.co[0][2]=512;
        wa.src[0][3]=W_ih[0]; wa.rs[0][3]=1024; wa.co[0][3]=0;
        wa.src[1][0]=W_ih[1]; wa.rs[1][0]=1536; wa.co[1][0]=0;
        wa.src[1][1]=W_hh[1]; wa.rs[1][1]=512;  wa.co[1][1]=0;
        wa.src[1][2]=W_ih[1]; wa.rs[1][2]=1536; wa.co[1][2]=1024;
        wa.src[1][3]=W_ih[1]; wa.rs[1][3]=1536; wa.co[1][3]=512;
        wa.src[2][0]=W_ih[2]; wa.rs[2][0]=1024; wa.co[2][0]=0;
        wa.src[2][1]=W_hh[2]; wa.rs[2][1]=512;  wa.co[2][1]=0;
        wa.src[2][2]=W_ih[2]; wa.rs[2][2]=1024; wa.co[2][2]=512;
        wa.src[2][3]=W_ih[2]; wa.rs[2][3]=1024; wa.co[2][3]=0;
        wa.nch[0]=24; wa.nch[1]=32; wa.nch[2]=24;
        wa.cnt[0]=393216; wa.cnt[1]=524288; wa.cnt[2]=393216;
        wa.slab[0]=0; wa.slab[1]=3145728; wa.slab[2]=7340032;
        wa.dst = wreg;
        conv_w<<<dim3(2048, 3), 256, 0, stream>>>(wa);
    }
    {
        XConv xa;
        xa.src[0] = x[0]; xa.src[1] = x[1]; xa.src[2] = x[2];
        xa.dst = xreg;
        conv_x<<<dim3(4096, 3), 256, 0, stream>>>(xa);
    }

    PersArgs pa;
    pa.wreg = wreg; pa.xreg = xreg; pa.hreg = hreg;
    pa.dx = dx; pa.out = out; pa.flags = flags;
    for (int l = 0; l < 3; ++l) { pa.bih[l] = b_ih[l]; pa.bhh[l] = b_hh[l]; }
    persistent_kernel<<<dim3(96), 512, 0, stream>>>(pa);
}

// Round 19
// 3294.434 us; speedup vs baseline: 1.1085x; 1.1085x over previous
//
#include <hip/hip_runtime.h>
#include <math.h>

#define BB 64
#define TT 256
#define HH 512
#define TH (TT*HH)
#define BTH (BB*TT*HH)

typedef __attribute__((ext_vector_type(8))) short short8;
typedef __attribute__((ext_vector_type(4))) float f32x4;

__device__ __forceinline__ unsigned short f32_bf16(float f) {
    unsigned int u = __float_as_uint(f);
    return (unsigned short)((u + 0x7fffu + ((u >> 16) & 1u)) >> 16);
}

// fast, overflow-safe gate nonlinearities (v_exp_f32 path; absmax-validated R9/R10)
__device__ __forceinline__ float sigm_f(float x) {
    return 1.f / (1.f + __expf(-x));
}
__device__ __forceinline__ float tanh_f(float x) {
    return 1.f - 2.f / (__expf(2.f * x) + 1.f);   // +inf->1, -inf->-1, no NaN
}

// coherent 16B fragment load: 2x u64 relaxed agent atomics (sc-bit loads
// bypass stale L1/L2; same mechanism as the flag polls)
__device__ __forceinline__ short8 ld_coh(const short* p) {
    const unsigned long long* q = (const unsigned long long*)p;
    unsigned long long a = __hip_atomic_load(q,     __ATOMIC_RELAXED, __HIP_MEMORY_SCOPE_AGENT);
    unsigned long long b = __hip_atomic_load(q + 1, __ATOMIC_RELAXED, __HIP_MEMORY_SCOPE_AGENT);
    union { unsigned long long u[2]; short8 s; } r;
    r.u[0] = a; r.u[1] = b;
    return r.s;
}

// ---- one-time: weights fp32 -> bf16, register-resident layout (R8 slabs) ----
struct WConv2 {
    const float* src[3][4];
    int rs[3][4];
    int co[3][4];
    int nch[3];
    int cnt[3];
    unsigned int slab[3];
    short* dst;
};
__global__ __launch_bounds__(256) void conv_w(WConv2 a) {
    const int l = blockIdx.y;
    const int i = blockIdx.x * 256 + threadIdx.x;
    if (i >= a.cnt[l]) return;
    const int NCH = a.nch[l];
    const int lane = i & 63;
    const int r = i >> 6;
    const int scc = r % NCH;
    const int wv = r / NCH;
    const int kh = wv & 1;
    const int nt = (wv >> 1) & 3;
    const int nb = wv >> 3;
    const int seg = scc >> 3;
    const int cc = scc & 7;
    const int hcol = nb*16 + nt*4 + ((lane & 15) >> 2);
    const int q = lane & 3;
    const int row = q*512 + hcol;
    const int k = a.co[l][seg] + (cc*2 + kh)*32 + (lane >> 4)*8;
    const float* s = a.src[l][seg] + (size_t)row * a.rs[l][seg] + k;
    float4 v0 = *(const float4*)s;
    float4 v1 = *(const float4*)(s + 4);
    short8 o;
    o[0]=f32_bf16(v0.x); o[1]=f32_bf16(v0.y); o[2]=f32_bf16(v0.z); o[3]=f32_bf16(v0.w);
    o[4]=f32_bf16(v1.x); o[5]=f32_bf16(v1.y); o[6]=f32_bf16(v1.z); o[7]=f32_bf16(v1.w);
    *(short8*)(a.dst + (size_t)a.slab[l] + (size_t)i * 8) = o;
}

// ---- one-time: x fp32 -> bf16 fragment-major (A-side) ----
struct XConv {
    const float* src[3];
    short* dst;
};
__global__ __launch_bounds__(256) void conv_x(XConv a) {
    const int l = blockIdx.y;
    const int i = blockIdx.x * 256 + threadIdx.x;
    const int lane = i & 63;
    const int kc = (i >> 6) & 15;
    const int btt = i >> 10;
    const int bt = btt & 3;
    const int t = btt >> 2;
    const int b = bt * 16 + (lane & 15);
    const int k = kc * 32 + (lane >> 4) * 8;
    const float* s = a.src[l] + ((size_t)b * TT + t) * HH + k;
    float4 v0 = *(const float4*)s;
    float4 v1 = *(const float4*)(s + 4);
    short8 o;
    o[0]=f32_bf16(v0.x); o[1]=f32_bf16(v0.y); o[2]=f32_bf16(v0.z); o[3]=f32_bf16(v0.w);
    o[4]=f32_bf16(v1.x); o[5]=f32_bf16(v1.y); o[6]=f32_bf16(v1.z); o[7]=f32_bf16(v1.w);
    *(short8*)(a.dst + (size_t)l * 8388608 + (size_t)i * 8) = o;
}

struct PersArgs {
    const short* wreg; const short* xreg; short* hreg;
    const float* dx; float* out; int* flags;
    const float* bih[3]; const float* bhh[3];
};

// plain-cached A loads (x segment; L2-cached, overlaps producer)
#define SEG_MFMA_PLAIN(SB, ASRC, SCP)                                          \
    {                                                                          \
        const short* ap_ = (ASRC) + (size_t)lane * 8;                          \
        _Pragma("unroll")                                                      \
        for (int cc = 0; cc < 8; ++cc) {                                       \
            const int cis = cc*2 + kh;                                         \
            short8 av[4];                                                      \
            _Pragma("unroll")                                                  \
            for (int mt = 0; mt < 4; ++mt)                                     \
                av[mt] = *(const short8*)(ap_ + (size_t)(mt*16 + cis) * 512);  \
            _Pragma("unroll")                                                  \
            for (int mt = 0; mt < 4; ++mt) {                                   \
                short8 xa = ((SCP) == nullptr || (SCP)[mt] != 0.f) ? av[mt] : vz; \
                acc[mt] = __builtin_amdgcn_mfma_f32_16x16x32_bf16(             \
                    xa, w[(SB) + cc], acc[mt], 0, 0, 0);                       \
            }                                                                  \
        }                                                                      \
    }

// consume one staged half (mt = MT0, MT0+1) from LDS
#define SEG_LDSMM_H(SB, ABUF, SCP, MT0)                                        \
    _Pragma("unroll")                                                          \
    for (int cc = 0; cc < 8; ++cc) {                                           \
        _Pragma("unroll")                                                      \
        for (int m2 = 0; m2 < 2; ++m2) {                                       \
            short8 av = *(const short8*)((ABUF) + (size_t)(m2*16 + cc*2 + kh)*512 + lane*8); \
            short8 xa = ((SCP) == nullptr || (SCP)[(MT0)+m2] != 0.f) ? av : vz; \
            acc[(MT0)+m2] = __builtin_amdgcn_mfma_f32_16x16x32_bf16(           \
                xa, w[(SB) + cc], acc[(MT0)+m2], 0, 0, 0);                     \
        }                                                                      \
    }

// full coherent segment via LDS bulk-staging with BOTH halves' loads issued
// up front. Barrier 1 is a RAW s_barrier preceded by lgkmcnt(0) only (the
// ds_writes of half A) -- NOT the compiler's vmcnt(0)-draining __syncthreads,
// so half B's 4 coherent loads stay in flight across it and their round trip
// hides under {write A, barrier, MFMA A}. sched_barrier(0) pins ordering
// (rule-18 guard). Barrier 2 is a normal __syncthreads (vmcnt already 0).
#define SEG_COH_LDS(SB, ASRC, SCP)                                             \
    {                                                                          \
        const short* spA_ = (ASRC) + ((size_t)(wv*4))*512 + lane*8;            \
        const short* spB_ = (ASRC) + ((size_t)(32 + wv*4))*512 + lane*8;       \
        short8 a0_ = ld_coh(spA_);                                             \
        short8 a1_ = ld_coh(spA_ + 512);                                       \
        short8 a2_ = ld_coh(spA_ + 1024);                                      \
        short8 a3_ = ld_coh(spA_ + 1536);                                      \
        short8 b0_ = ld_coh(spB_);                                             \
        short8 b1_ = ld_coh(spB_ + 512);                                       \
        short8 b2_ = ld_coh(spB_ + 1024);                                      \
        short8 b3_ = ld_coh(spB_ + 1536);                                      \
        {                                                                      \
            short* dp_ = abufA + (wv*4)*512 + lane*8;                          \
            *(short8*)(dp_)        = a0_;                                      \
            *(short8*)(dp_ + 512)  = a1_;                                      \
            *(short8*)(dp_ + 1024) = a2_;                                      \
            *(short8*)(dp_ + 1536) = a3_;                                      \
        }                                                                      \
        asm volatile("s_waitcnt lgkmcnt(0)" ::: "memory");                     \
        __builtin_amdgcn_s_barrier();                                          \
        __builtin_amdgcn_sched_barrier(0);                                     \
        SEG_LDSMM_H(SB, abufA, SCP, 0);                                        \
        {                                                                      \
            short* dpB_ = abufB + (wv*4)*512 + lane*8;                         \
            *(short8*)(dpB_)        = b0_;                                     \
            *(short8*)(dpB_ + 512)  = b1_;                                     \
            *(short8*)(dpB_ + 1024) = b2_;                                     \
            *(short8*)(dpB_ + 1536) = b3_;                                     \
        }                                                                      \
        __syncthreads();                                                       \
        SEG_LDSMM_H(SB, abufB, SCP, 2);                                        \
    }

template<int L>
__device__ __forceinline__ void run_layer(const PersArgs& a, int nb,
                                          char* smem) {
    constexpr int NSEG = (L == 1) ? 4 : 3;
    constexpr int NCH  = NSEG * 8;
    constexpr unsigned int WSLAB = (L == 0) ? 0u : ((L == 1) ? 3145728u : 7340032u);
    // LDS: [0,32768) = staging buffer A, ALIASED with gsh (epilogue).
    //      [32768,65536) = staging buffer B.
    // Alias safety: last abufA reads (MFMA A of last segment) precede that
    // segment's barrier 2; gsh writes come after it. Epilogue gsh reads are
    // separated from the next stage's abufA writes by the drain barrier.
    short* abufA = (short*)smem;
    short* abufB = (short*)(smem + 32768);
    float* gsh   = (float*)smem;
    #define GSH(khi, nti, mti, ri, ci) gsh[((((khi)*4 + (nti))*4 + (mti))*16 + (ri))*16 + (ci)]

    const int tid  = threadIdx.x;
    const int lane = tid & 63;
    const int wv   = tid >> 6;
    const int nt   = wv >> 1;
    const int kh   = wv & 1;
    const int r16  = lane & 15;
    const short8 vz = {0,0,0,0,0,0,0,0};

    // weight slice -> registers/AGPRs (unified file), lives across all 256 t
    short8 w[NCH];
    {
        const short* wb = a.wreg + WSLAB
            + ((size_t)((nb*8 + nt*2 + kh) * NCH)) * 512 + lane * 8;
        #pragma unroll
        for (int i = 0; i < NCH; ++i)
            w[i] = *(const short8*)(wb + (size_t)i * 512);
    }

    const int eb_b = tid >> 3;
    const int ehp  = tid & 7;
    float bias[2][4];
    #pragma unroll
    for (int e = 0; e < 2; ++e) {
        const int ec = nb*16 + 2*ehp + e;
        #pragma unroll
        for (int q = 0; q < 4; ++q)
            bias[e][q] = a.bih[L][q*512 + ec] + a.bhh[L][q*512 + ec];
    }
    float c_reg[2] = {0.f, 0.f}, h_reg[2] = {0.f, 0.f};
    float hprev[2] = {0.f, 0.f};   // deferred out-store values (stage t-1)

    // wave0 32-lane poll on one stage's flag group; barrier releases block
    auto poll32 = [&](int st) {
        if (wv == 0) {
            const int* f = a.flags + st*32;
            for (;;) {
                int v = 1;
                if (lane < 32)
                    v = __hip_atomic_load(f + lane, __ATOMIC_RELAXED, __HIP_MEMORY_SCOPE_AGENT);
                if (__all(v != 0)) break;
                __builtin_amdgcn_s_sleep(1);
            }
        }
        __syncthreads();
    };

    for (int t = 0; t < TT; ++t) {
        const int pprev = (t - 1) & 1, pcur = t & 1;
        float dbv[4], dvv[4];
        #pragma unroll
        for (int mt = 0; mt < 4; ++mt) {
            const int b = mt*16 + r16;
            dbv[mt] = (L == 0) ? 1.f : a.dx[b*768 + (L-1)*256 + t];
            dvv[mt] = (t == 0) ? 0.f : a.dx[b*768 + L*256 + (t-1)];
        }
        f32x4 acc[4];
        #pragma unroll
        for (int mt = 0; mt < 4; ++mt) acc[mt] = (f32x4){0.f, 0.f, 0.f, 0.f};

        // ---- x segment: no dependency, runs before any poll ----
        SEG_MFMA_PLAIN(0, a.xreg + (size_t)L*8388608 + (size_t)t*32768,
                       (L == 0) ? (const float*)nullptr : dbv);

        if (t > 0) {
            // ---- hh: 2-links-stale dependency, poll first (usually instant) ----
            poll32((t-1)*3 + L);
            // deferred HBM out-store of stage t-1: ack overlaps hh staging
            {
                union { float f[2]; unsigned long long u; } pk;
                pk.f[0] = hprev[0]; pk.f[1] = hprev[1];
                __builtin_nontemporal_store(pk.u,
                    (unsigned long long*)(a.out + (size_t)L*BTH + (size_t)eb_b*TH
                                          + (size_t)(t-1)*HH + nb*16 + 2*ehp));
            }
            SEG_COH_LDS(8, a.hreg + (size_t)(L*2 + pprev)*32768, (const float*)nullptr);
            // ---- td: 1-link-fresh, poll after hh work is done ----
            if (L < 2) {
                poll32((t-1)*3 + L + 1);
                SEG_COH_LDS(16, a.hreg + (size_t)((L+1)*2 + pprev)*32768, dvv);
            }
        }
        // ---- bu: freshest (same-t), last ----
        if (L > 0) {
            poll32(t*3 + L - 1);
            SEG_COH_LDS(NCH - 8, a.hreg + (size_t)((L-1)*2 + pcur)*32768, dbv);
        }

        // ---- acc -> LDS exchange (gsh aliases abufA; last segment's
        //      barrier 2 already separates its MFMA-A reads) ----
        #pragma unroll
        for (int mt = 0; mt < 4; ++mt)
            #pragma unroll
            for (int r = 0; r < 4; ++r)
                GSH(kh, nt, mt, (lane >> 4)*4 + r, r16) = acc[mt][r];
        __syncthreads();

        // ---- cell epilogue: 512 threads x 2 hcols ----
        float hval[2];
        {
            const float db2 = (L == 0) ? 1.f : a.dx[eb_b*768 + (L-1)*256 + t];
            const float d2  = (t == 0) ? 0.f : a.dx[eb_b*768 + L*256 + (t-1)];
            const bool copy = (db2 + d2 == 0.f);
            const int mt = eb_b >> 4, row = eb_b & 15;
            #pragma unroll
            for (int e = 0; e < 2; ++e) {
                const int hl = 2*ehp + e;
                const int ntE = hl >> 2, cb = (hl & 3)*4;
                float G[4];
                #pragma unroll
                for (int q = 0; q < 4; ++q)
                    G[q] = GSH(0, ntE, mt, row, cb+q) + GSH(1, ntE, mt, row, cb+q) + bias[e][q];
                const float i_ = sigm_f(G[0]);
                const float f_ = sigm_f(G[1]);
                const float g_ = tanh_f(G[2]);
                const float o_ = sigm_f(G[3]);
                const float cold = c_reg[e] * (1.f - d2);
                const float cn = f_*cold + i_*g_;
                const float hn = o_*tanh_f(cn);
                hval[e] = copy ? h_reg[e] : hn;
                c_reg[e] = copy ? cold : cn;
                h_reg[e] = hval[e];
            }
            unsigned int pack = (unsigned int)f32_bf16(hval[0])
                              | ((unsigned int)f32_bf16(hval[1]) << 16);
            const int k  = nb*16 + 2*ehp;
            const int kc = k >> 5, kk = k & 31;
            const int lhi = kk >> 3, j = kk & 7;
            unsigned int* dst = (unsigned int*)(a.hreg + (size_t)(L*2 + pcur)*32768)
                + ((((size_t)(mt*16 + kc))*64 + lhi*16 + row)*8 + j) / 2;
            __hip_atomic_store(dst, pack, __ATOMIC_RELAXED, __HIP_MEMORY_SCOPE_AGENT);
        }
        __syncthreads();   // per-thread vmcnt drained before barrier -> stores visible

        if (tid == 0)      // relaxed: ordering via drained stores + barrier + ctrl dep
            __hip_atomic_store(a.flags + (t*3 + L)*32 + nb, 1,
                               __ATOMIC_RELAXED, __HIP_MEMORY_SCOPE_AGENT);

        hprev[0] = hval[0]; hprev[1] = hval[1];
    }
    // flush final timestep's out-store
    {
        union { float f[2]; unsigned long long u; } pk;
        pk.f[0] = hprev[0]; pk.f[1] = hprev[1];
        __builtin_nontemporal_store(pk.u,
            (unsigned long long*)(a.out + (size_t)L*BTH + (size_t)eb_b*TH
                                  + (size_t)(TT-1)*HH + nb*16 + 2*ehp));
    }
    #undef GSH
}

__global__ __launch_bounds__(512, 2) void persistent_kernel(PersArgs a) {
    __shared__ char smem[65536];
    const int bid = blockIdx.x;
    if (bid < 32)       run_layer<0>(a, bid, smem);
    else if (bid < 64)  run_layer<1>(a, bid - 32, smem);
    else                run_layer<2>(a, bid - 64, smem);
}

extern "C" void kernel_launch(void* const* d_in, const int* in_sizes, int n_in,
                              void* d_out, int out_size, void* d_ws, size_t ws_size,
                              hipStream_t stream) {
    const float* x[3]    = {(const float*)d_in[0], (const float*)d_in[1], (const float*)d_in[2]};
    const float* dx      = (const float*)d_in[3];
    const float* W_ih[3] = {(const float*)d_in[4], (const float*)d_in[8],  (const float*)d_in[12]};
    const float* W_hh[3] = {(const float*)d_in[5], (const float*)d_in[9],  (const float*)d_in[13]};
    const float* b_ih[3] = {(const float*)d_in[6], (const float*)d_in[10], (const float*)d_in[14]};
    const float* b_hh[3] = {(const float*)d_in[7], (const float*)d_in[11], (const float*)d_in[15]};
    float* out = (float*)d_out;

    char* ws = (char*)d_ws;
    const size_t SZ_FLAGS = 98304;                  // 768*32 ints
    const size_t SZ_WREG  = 20971520;
    const size_t SZ_XREG  = 50331648;
    int*   flags = (int*)ws;
    short* wreg  = (short*)(ws + SZ_FLAGS);
    short* xreg  = (short*)(ws + SZ_FLAGS + SZ_WREG);
    short* hreg  = (short*)(ws + SZ_FLAGS + SZ_WREG + SZ_XREG);

    hipMemsetAsync(flags, 0, SZ_FLAGS, stream);

    {   // weight conversion: seg order per layer = [x, hh, td, bu] (R8 slabs)
        WConv2 wa;
        wa.src[0][0]=W_ih[0]; wa.rs[0][0]=1024; wa.co[0][0]=0;
        wa.src[0][1]=W_hh[0]; wa.rs[0][1]=512;  wa.co[0][1]=0;
        wa.src[0][2]=W_ih[0]; wa.rs[0][2]=1024; wa.co[0][2]=512;
        wa.src[0][3]=W_ih[0]; wa.rs[0][3]=1024; wa.co[0][3]=0;
        wa.src[1][0]=W_ih[1]; wa.rs[1][0]=1536; wa.co[1][0]=0;
        wa.src[1][1]=W_hh[1]; wa.rs[1][1]=512;  wa.co[1][1]=0;
        wa.src[1][2]=W_ih[1]; wa.rs[1][2]=1536; wa.co[1][2]=1024;
        wa.src[1][3]=W_ih[1]; wa.rs[1][3]=1536; wa.co[1][3]=512;
        wa.src[2][0]=W_ih[2]; wa.rs[2][0]=1024; wa.co[2][0]=0;
        wa.src[2][1]=W_hh[2]; wa.rs[2][1]=512;  wa.co[2][1]=0;
        wa.src[2][2]=W_ih[2]; wa.rs[2][2]=1024; wa.co[2][2]=512;
        wa.src[2][3]=W_ih[2]; wa.rs[2][3]=1024; wa.co[2][3]=0;
        wa.nch[0]=24; wa.nch[1]=32; wa.nch[2]=24;
        wa.cnt[0]=393216; wa.cnt[1]=524288; wa.cnt[2]=393216;
        wa.slab[0]=0; wa.slab[1]=3145728; wa.slab[2]=7340032;
        wa.dst = wreg;
        conv_w<<<dim3(2048, 3), 256, 0, stream>>>(wa);
    }
    {
        XConv xa;
        xa.src[0] = x[0]; xa.src[1] = x[1]; xa.src[2] = x[2];
        xa.dst = xreg;
        conv_x<<<dim3(4096, 3), 256, 0, stream>>>(xa);
    }

    PersArgs pa;
    pa.wreg = wreg; pa.xreg = xreg; pa.hreg = hreg;
    pa.dx = dx; pa.out = out; pa.flags = flags;
    for (int l = 0; l < 3; ++l) { pa.bih[l] = b_ih[l]; pa.bhh[l] = b_hh[l]; }
    persistent_kernel<<<dim3(96), 512, 0, stream>>>(pa);
}